// Round 1
// baseline (286.086 us; speedup 1.0000x reference)
//
#include <hip/hip_runtime.h>
#include <hip/hip_bf16.h>

// ---------- types ----------
typedef __bf16 bf16x8 __attribute__((ext_vector_type(8)));      // 16B, MFMA A/B frag
typedef float  f32x4  __attribute__((ext_vector_type(4)));      // MFMA C/D frag
typedef unsigned short ushort4v __attribute__((ext_vector_type(4)));

static __device__ __forceinline__ float bf2f(unsigned short u) {
  union { float f; unsigned int i; } v; v.i = ((unsigned int)u) << 16; return v.f;
}
static __device__ __forceinline__ unsigned short f2bf(float f) {
  unsigned int x = __float_as_uint(f);
  x += 0x7fffu + ((x >> 16) & 1u);   // RNE (inputs are NaN-free)
  return (unsigned short)(x >> 16);
}

// ---------- K0: weights -> bf16, transposed to [N][K] ----------
// W1T [1024][512]: cols 0..767 = h_qkv_w, 768..1023 = l_q_w
// W2T [512][512] = l_kv_w^T ;  W3T [512][256]: rows 0..255 h_proj_w^T, 256.. l_proj_w^T
__global__ __launch_bounds__(256)
void prep_weights(const float* __restrict__ lq,  const float* __restrict__ lkv,
                  const float* __restrict__ lpw, const float* __restrict__ lpb,
                  const float* __restrict__ hqkv,const float* __restrict__ hpw,
                  const float* __restrict__ hpb,
                  unsigned short* __restrict__ W1T, unsigned short* __restrict__ W2T,
                  unsigned short* __restrict__ W3T, float* __restrict__ bcat)
{
  int idx = blockIdx.x * 256 + threadIdx.x;
  const int T1 = 524288, T2 = T1 + 262144, T3 = T2 + 131072, T4 = T3 + 512;
  if (idx >= T4) return;
  if (idx < T1) {
    int n = idx >> 9, k = idx & 511;
    float v = (n < 768) ? hqkv[k * 768 + n] : lq[k * 256 + (n - 768)];
    W1T[idx] = f2bf(v);
  } else if (idx < T2) {
    int i2 = idx - T1; int n = i2 >> 9, k = i2 & 511;
    W2T[i2] = f2bf(lkv[k * 512 + n]);
  } else if (idx < T3) {
    int i3 = idx - T2; int n = i3 >> 8, k = i3 & 255;
    float v = (n < 256) ? hpw[k * 256 + n] : lpw[k * 256 + (n - 256)];
    W3T[i3] = f2bf(v);
  } else {
    int i4 = idx - T3;
    bcat[i4] = (i4 < 256) ? hpb[i4] : lpb[i4 - 256];
  }
}

// ---------- K0b: x -> xw bf16 (window-major) + pooled bf16 (window mean) ----------
__global__ __launch_bounds__(128)
void prep_x(const float* __restrict__ x, unsigned short* __restrict__ xw,
            unsigned short* __restrict__ pooled)
{
  int win = blockIdx.x;                 // b*1024 + t
  int b = win >> 10, t = win & 1023;
  int wy = t >> 5, wx = t & 31;
  int c0 = threadIdx.x * 4;
  const float* xb = x + ((size_t)(b << 12)) * 512;
  float ax = 0.f, ay = 0.f, az = 0.f, aw = 0.f;
  #pragma unroll
  for (int wl = 0; wl < 4; wl++) {
    int y = wy * 2 + (wl >> 1), xc = wx * 2 + (wl & 1);
    const float4 v = *(const float4*)(xb + (size_t)(y * 64 + xc) * 512 + c0);
    ax += v.x; ay += v.y; az += v.z; aw += v.w;
    ushort4v o = { f2bf(v.x), f2bf(v.y), f2bf(v.z), f2bf(v.w) };
    *(ushort4v*)(xw + (size_t)(win * 4 + wl) * 512 + c0) = o;
  }
  ushort4v p = { f2bf(ax * 0.25f), f2bf(ay * 0.25f), f2bf(az * 0.25f), f2bf(aw * 0.25f) };
  *(ushort4v*)(pooled + (size_t)win * 512 + c0) = p;
}

// ---------- generic NT bf16 GEMM: C[M,N] = A[M,K] * Bt[N,K]^T ----------
// EPI 0: store bf16 C row-major [M][N]         (QKV|Q gemm)
// EPI 1: split store: col<256 -> kv_k[8192][256]; col>=256 -> vT[(b*4+h)*64+d][1024]
// EPI 2: A = (n0<256 ? A0 : A1), + bias, permute window-major row -> raster, fp32 out
template<int EPI>
__global__ __launch_bounds__(256)
void gemm_nt(const unsigned short* __restrict__ A0,
             const unsigned short* __restrict__ A1,
             const unsigned short* __restrict__ Bt,
             unsigned short* __restrict__ C0,
             unsigned short* __restrict__ C1,
             float* __restrict__ Cf,
             const float* __restrict__ bias,
             int M, int N, int K)
{
  __shared__ unsigned short Asm[128 * 64];
  __shared__ unsigned short Bsm[128 * 64];
  char* As = (char*)Asm; char* Bs = (char*)Bsm;
  const int tid = threadIdx.x;
  const int w = tid >> 6, l = tid & 63;
  const int ntiles = N >> 7;
  const int mt = blockIdx.x / ntiles, nt = blockIdx.x % ntiles;
  const int m0 = mt * 128, n0 = nt * 128;
  const unsigned short* A = (EPI == 2 && n0 >= 256) ? A1 : A0;

  const int wm = (w >> 1) * 64, wn = (w & 1) * 64;
  f32x4 acc[4][4];
  #pragma unroll
  for (int i = 0; i < 4; i++)
    #pragma unroll
    for (int j = 0; j < 4; j++) acc[i][j] = (f32x4){0.f, 0.f, 0.f, 0.f};

  for (int k0 = 0; k0 < K; k0 += 64) {
    bf16x8 av[4], bv[4];
    #pragma unroll
    for (int i = 0; i < 4; i++) {
      int r = i * 32 + w * 8 + (l >> 3);
      av[i] = *(const bf16x8*)(A  + (size_t)(m0 + r) * K + k0 + (l & 7) * 8);
      bv[i] = *(const bf16x8*)(Bt + (size_t)(n0 + r) * K + k0 + (l & 7) * 8);
    }
    __syncthreads();
    #pragma unroll
    for (int i = 0; i < 4; i++) {
      int r = i * 32 + w * 8 + (l >> 3);
      int off = (r * 128 + (l & 7) * 16) ^ ((r & 7) << 4);   // XOR-swizzle (G4)
      *(bf16x8*)(As + off) = av[i];
      *(bf16x8*)(Bs + off) = bv[i];
    }
    __syncthreads();
    #pragma unroll
    for (int kk = 0; kk < 2; kk++) {
      bf16x8 af[4], bfr[4];
      #pragma unroll
      for (int m = 0; m < 4; m++) {
        int r = wm + m * 16 + (l & 15);
        af[m] = *(const bf16x8*)(As + ((r * 128 + kk * 64 + (l >> 4) * 16) ^ ((r & 7) << 4)));
      }
      #pragma unroll
      for (int n = 0; n < 4; n++) {
        int r = wn + n * 16 + (l & 15);
        bfr[n] = *(const bf16x8*)(Bs + ((r * 128 + kk * 64 + (l >> 4) * 16) ^ ((r & 7) << 4)));
      }
      #pragma unroll
      for (int m = 0; m < 4; m++)
        #pragma unroll
        for (int n = 0; n < 4; n++)
          acc[m][n] = __builtin_amdgcn_mfma_f32_16x16x32_bf16(af[m], bfr[n], acc[m][n], 0, 0, 0);
    }
  }

  const int crow0 = m0 + wm, ccol0 = n0 + wn;
  #pragma unroll
  for (int m = 0; m < 4; m++) {
    #pragma unroll
    for (int n = 0; n < 4; n++) {
      #pragma unroll
      for (int j = 0; j < 4; j++) {
        int row = crow0 + m * 16 + (l >> 4) * 4 + j;
        int col = ccol0 + n * 16 + (l & 15);
        float v = acc[m][n][j];
        if (EPI == 0) {
          C0[(size_t)row * N + col] = f2bf(v);
        } else if (EPI == 1) {
          if (col < 256) C0[(size_t)row * 256 + col] = f2bf(v);
          else {
            int h = (col - 256) >> 6, d = (col - 256) & 63;
            int b = row >> 10, key = row & 1023;
            C1[(size_t)(((b * 4 + h) << 6) + d) * 1024 + key] = f2bf(v);
          }
        } else {
          float vv = v + bias[col];
          int b = row >> 12, r = row & 4095, t = r >> 2, wl = r & 3;
          int y = ((t >> 5) << 1) | (wl >> 1), xc = ((t & 31) << 1) | (wl & 1);
          Cf[(size_t)((b << 12) + y * 64 + xc) * 512 + col] = vv;
        }
      }
    }
  }
}

// ---------- K3: hifi 2x2-window attention. 1 wave = 1 window, all 4 heads ----------
__global__ __launch_bounds__(256)
void hifi_attn(const unsigned short* __restrict__ QKVQ, unsigned short* __restrict__ aoh)
{
  int widx = blockIdx.x * 4 + (threadIdx.x >> 6);
  int l = threadIdx.x & 63;
  int h = l >> 4, i = (l >> 2) & 3, j = l & 3;
  size_t r0 = (size_t)widx * 4;
  const unsigned short* qp = QKVQ + (r0 + i) * 1024 + h * 64;
  const unsigned short* kp = QKVQ + (r0 + j) * 1024 + 256 + h * 64;
  float s = 0.f;
  #pragma unroll
  for (int c = 0; c < 8; c++) {
    bf16x8 q8 = *(const bf16x8*)(qp + c * 8);
    bf16x8 k8 = *(const bf16x8*)(kp + c * 8);
    #pragma unroll
    for (int e = 0; e < 8; e++) s += (float)q8[e] * (float)k8[e];
  }
  s *= 0.125f;
  float mx = fmaxf(s, __shfl_xor(s, 1)); mx = fmaxf(mx, __shfl_xor(mx, 2));
  float p = __expf(s - mx);
  float sum = p + __shfl_xor(p, 1); sum += __shfl_xor(sum, 2);
  p /= sum;

  // lane role switch: (h, dblk) for output
  int dblk = l & 15;
  float o[4][4];
  #pragma unroll
  for (int ii = 0; ii < 4; ii++)
    #pragma unroll
    for (int e = 0; e < 4; e++) o[ii][e] = 0.f;
  #pragma unroll
  for (int jj = 0; jj < 4; jj++) {
    const unsigned short* vp = QKVQ + (r0 + jj) * 1024 + 512 + h * 64 + dblk * 4;
    ushort4v v4 = *(const ushort4v*)vp;
    #pragma unroll
    for (int ii = 0; ii < 4; ii++) {
      float pij = __shfl(p, (l & 48) + ii * 4 + jj);
      #pragma unroll
      for (int e = 0; e < 4; e++) o[ii][e] += pij * bf2f(v4[e]);
    }
  }
  #pragma unroll
  for (int ii = 0; ii < 4; ii++) {
    ushort4v ov = { f2bf(o[ii][0]), f2bf(o[ii][1]), f2bf(o[ii][2]), f2bf(o[ii][3]) };
    *(ushort4v*)(aoh + (r0 + ii) * 256 + h * 64 + dblk * 4) = ov;
  }
}

// ---------- K4: lofi flash attention over 1024 pooled keys ----------
// block = (b,h,qtile64); wave = 16 query rows; KV chunk = 32 keys
__global__ __launch_bounds__(256)
void lofi_attn(const unsigned short* __restrict__ QKVQ,
               const unsigned short* __restrict__ kvk,
               const unsigned short* __restrict__ vT,
               unsigned short* __restrict__ aol)
{
  __shared__ unsigned short Ksm[32 * 64];     // [key][d], XOR-swizzled
  __shared__ unsigned short Vsm[64 * 40];     // [d][key], stride 40 keys
  __shared__ unsigned short Psm[4][512];      // per-wave P [16][32], XOR-swizzled
  char* Ks = (char*)Ksm; char* Vs = (char*)Vsm;

  const int tid = threadIdx.x, w = tid >> 6, l = tid & 63;
  const int bh = blockIdx.x >> 6, qt = blockIdx.x & 63;
  const int b = bh >> 2, h = bh & 3;
  char* Ps = (char*)&Psm[w][0];

  const int qrow = (b << 12) + qt * 64 + w * 16 + (l & 15);
  const unsigned short* qp = QKVQ + (size_t)qrow * 1024 + 768 + h * 64 + (l >> 4) * 8;
  bf16x8 a0 = *(const bf16x8*)qp;
  bf16x8 a1 = *(const bf16x8*)(qp + 32);

  float m_run[4], l_run[4];
  #pragma unroll
  for (int j = 0; j < 4; j++) { m_run[j] = -1e30f; l_run[j] = 0.f; }
  f32x4 accO[4];
  #pragma unroll
  for (int d = 0; d < 4; d++) accO[d] = (f32x4){0.f, 0.f, 0.f, 0.f};

  const int skey = tid >> 3, sd0 = (tid & 7) * 8;
  const unsigned short* ksrc = kvk + ((size_t)((b << 10) + skey)) * 256 + h * 64 + sd0;
  const int vd = tid >> 2, vk0 = (tid & 3) * 8;
  const unsigned short* vsrc = vT + ((size_t)(bh * 64 + vd)) * 1024 + vk0;

  for (int c = 0; c < 32; c++) {
    bf16x8 k8 = *(const bf16x8*)(ksrc + (size_t)c * 32 * 256);
    bf16x8 v8 = *(const bf16x8*)(vsrc + c * 32);
    __syncthreads();
    *(bf16x8*)(Ks + ((skey * 128 + sd0 * 2) ^ ((skey & 7) << 4))) = k8;
    *(bf16x8*)(Vs + (vd * 80 + vk0 * 2)) = v8;
    __syncthreads();

    // --- QK^T: S[16 rows][32 keys] ---
    f32x4 s0 = (f32x4){0.f,0.f,0.f,0.f}, s1 = (f32x4){0.f,0.f,0.f,0.f};
    const int key0 = l & 15, key1 = 16 + (l & 15);
    #pragma unroll
    for (int kk = 0; kk < 2; kk++) {
      bf16x8 bk0 = *(const bf16x8*)(Ks + ((key0 * 128 + kk * 64 + (l >> 4) * 16) ^ ((key0 & 7) << 4)));
      bf16x8 bk1 = *(const bf16x8*)(Ks + ((key1 * 128 + kk * 64 + (l >> 4) * 16) ^ ((key1 & 7) << 4)));
      bf16x8 aa = kk ? a1 : a0;
      s0 = __builtin_amdgcn_mfma_f32_16x16x32_bf16(aa, bk0, s0, 0, 0, 0);
      s1 = __builtin_amdgcn_mfma_f32_16x16x32_bf16(aa, bk1, s1, 0, 0, 0);
    }
    // --- online softmax (rows distributed: row=(l>>4)*4+j, cols {l&15,16+(l&15)}) ---
    #pragma unroll
    for (int j = 0; j < 4; j++) {
      float v0 = s0[j] * 0.125f, v1 = s1[j] * 0.125f;
      float mx = fmaxf(v0, v1);
      mx = fmaxf(mx, __shfl_xor(mx, 1)); mx = fmaxf(mx, __shfl_xor(mx, 2));
      mx = fmaxf(mx, __shfl_xor(mx, 4)); mx = fmaxf(mx, __shfl_xor(mx, 8));
      float m_new = fmaxf(m_run[j], mx);
      float alpha = __expf(m_run[j] - m_new);
      float p0 = __expf(v0 - m_new), p1 = __expf(v1 - m_new);
      float rs = p0 + p1;
      rs += __shfl_xor(rs, 1); rs += __shfl_xor(rs, 2);
      rs += __shfl_xor(rs, 4); rs += __shfl_xor(rs, 8);
      l_run[j] = l_run[j] * alpha + rs;
      m_run[j] = m_new;
      #pragma unroll
      for (int d = 0; d < 4; d++) accO[d][j] *= alpha;
      int prow = (l >> 4) * 4 + j;
      *(unsigned short*)(Ps + ((prow * 64 + (l & 15) * 2)      ^ ((prow & 7) << 4))) = f2bf(p0);
      *(unsigned short*)(Ps + ((prow * 64 + 32 + (l & 15) * 2) ^ ((prow & 7) << 4))) = f2bf(p1);
    }
    // --- PV: O += P[16x32] * V[32x64] ---
    {
      int prow = l & 15;
      bf16x8 pa = *(const bf16x8*)(Ps + ((prow * 64 + (l >> 4) * 16) ^ ((prow & 7) << 4)));
      #pragma unroll
      for (int d = 0; d < 4; d++) {
        bf16x8 bv = *(const bf16x8*)(Vs + ((d * 16 + (l & 15)) * 80 + (l >> 4) * 16));
        accO[d] = __builtin_amdgcn_mfma_f32_16x16x32_bf16(pa, bv, accO[d], 0, 0, 0);
      }
    }
  }

  int orow_base = (b << 12) + qt * 64 + w * 16;
  #pragma unroll
  for (int j = 0; j < 4; j++) {
    float inv = 1.f / l_run[j];
    int row = orow_base + (l >> 4) * 4 + j;
    #pragma unroll
    for (int d = 0; d < 4; d++)
      aol[(size_t)row * 256 + h * 64 + d * 16 + (l & 15)] = f2bf(accO[d][j] * inv);
  }
}

// ---------- launch ----------
extern "C" void kernel_launch(void* const* d_in, const int* in_sizes, int n_in,
                              void* d_out, int out_size, void* d_ws, size_t ws_size,
                              hipStream_t stream) {
  (void)in_sizes; (void)n_in; (void)out_size; (void)ws_size;
  const float* x     = (const float*)d_in[0];
  const float* lqw   = (const float*)d_in[3];
  const float* lkvw  = (const float*)d_in[4];
  const float* lpw   = (const float*)d_in[5];
  const float* lpb   = (const float*)d_in[6];
  const float* hqkvw = (const float*)d_in[7];
  const float* hpw   = (const float*)d_in[8];
  const float* hpb   = (const float*)d_in[9];

  char* ws = (char*)d_ws;
  unsigned short* W1T    = (unsigned short*)(ws + 0);
  unsigned short* W2T    = (unsigned short*)(ws + 1048576);
  unsigned short* W3T    = (unsigned short*)(ws + 1572864);
  float*          bcat   = (float*)        (ws + 1835008);
  unsigned short* xw     = (unsigned short*)(ws + 2097152);
  unsigned short* pooled = (unsigned short*)(ws + 35651584);
  unsigned short* kvk    = (unsigned short*)(ws + 44040192);
  unsigned short* vT     = (unsigned short*)(ws + 48234496);
  unsigned short* aoh    = (unsigned short*)(ws + 52428800);
  unsigned short* aol    = (unsigned short*)(ws + 69206016);
  // d_out (64 MiB) doubles as the bf16 qkv|q buffer; final proj overwrites it.
  unsigned short* QKVQ   = (unsigned short*)d_out;
  float*          out    = (float*)d_out;

  prep_weights<<<3586, 256, 0, stream>>>(lqw, lkvw, lpw, lpb, hqkvw, hpw, hpb,
                                         W1T, W2T, W3T, bcat);
  prep_x<<<8192, 128, 0, stream>>>(x, xw, pooled);
  // QKV|Q: [32768,512] x [512,1024]
  gemm_nt<0><<<2048, 256, 0, stream>>>(xw, nullptr, W1T, QKVQ, nullptr, nullptr, nullptr,
                                       32768, 1024, 512);
  // KV: [8192,512] x [512,512] -> kv_k + vT
  gemm_nt<1><<<256, 256, 0, stream>>>(pooled, nullptr, W2T, kvk, vT, nullptr, nullptr,
                                      8192, 512, 512);
  hifi_attn<<<2048, 256, 0, stream>>>(QKVQ, aoh);
  lofi_attn<<<2048, 256, 0, stream>>>(QKVQ, kvk, vT, aol);
  // proj: [32768,256] x [256,512] (+bias, un-permute, fp32)
  gemm_nt<2><<<1024, 256, 0, stream>>>(aoh, aol, W3T, nullptr, nullptr, out, bcat,
                                       32768, 512, 256);
}

// Round 2
// 206.069 us; speedup vs baseline: 1.3883x; 1.3883x over previous
//
#include <hip/hip_runtime.h>
#include <hip/hip_bf16.h>

// ---------- types ----------
typedef __bf16 bf16x8 __attribute__((ext_vector_type(8)));      // 16B, MFMA A/B frag
typedef float  f32x4  __attribute__((ext_vector_type(4)));      // MFMA C/D frag
typedef unsigned short ushort4v __attribute__((ext_vector_type(4)));

static __device__ __forceinline__ float bf2f(unsigned short u) {
  union { float f; unsigned int i; } v; v.i = ((unsigned int)u) << 16; return v.f;
}
static __device__ __forceinline__ unsigned short f2bf(float f) {
  unsigned int x = __float_as_uint(f);
  x += 0x7fffu + ((x >> 16) & 1u);   // RNE (inputs are NaN-free)
  return (unsigned short)(x >> 16);
}

// ---------- K0: weights -> bf16, transposed to [N][K] ----------
// W1T [1024][512]: cols 0..767 = h_qkv_w, 768..1023 = l_q_w
// Softmax scale (0.125, exact in bf16) folded into the q-producing columns:
// n<256 (hifi Wq) and n>=768 (lofi Wq).
__global__ __launch_bounds__(256)
void prep_weights(const float* __restrict__ lq,  const float* __restrict__ lkv,
                  const float* __restrict__ lpw, const float* __restrict__ lpb,
                  const float* __restrict__ hqkv,const float* __restrict__ hpw,
                  const float* __restrict__ hpb,
                  unsigned short* __restrict__ W1T, unsigned short* __restrict__ W2T,
                  unsigned short* __restrict__ W3T, float* __restrict__ bcat)
{
  int idx = blockIdx.x * 256 + threadIdx.x;
  const int T1 = 524288, T2 = T1 + 262144, T3 = T2 + 131072, T4 = T3 + 512;
  if (idx >= T4) return;
  if (idx < T1) {
    int n = idx >> 9, k = idx & 511;
    float v = (n < 768) ? hqkv[k * 768 + n] : lq[k * 256 + (n - 768)];
    if (n < 256 || n >= 768) v *= 0.125f;     // fold attention scale into Wq
    W1T[idx] = f2bf(v);
  } else if (idx < T2) {
    int i2 = idx - T1; int n = i2 >> 9, k = i2 & 511;
    W2T[i2] = f2bf(lkv[k * 512 + n]);
  } else if (idx < T3) {
    int i3 = idx - T2; int n = i3 >> 8, k = i3 & 255;
    float v = (n < 256) ? hpw[k * 256 + n] : lpw[k * 256 + (n - 256)];
    W3T[i3] = f2bf(v);
  } else {
    int i4 = idx - T3;
    bcat[i4] = (i4 < 256) ? hpb[i4] : lpb[i4 - 256];
  }
}

// ---------- K0b: x -> xw bf16 (window-major) + pooled bf16 (window mean) ----------
__global__ __launch_bounds__(128)
void prep_x(const float* __restrict__ x, unsigned short* __restrict__ xw,
            unsigned short* __restrict__ pooled)
{
  int win = blockIdx.x;                 // b*1024 + t
  int b = win >> 10, t = win & 1023;
  int wy = t >> 5, wx = t & 31;
  int c0 = threadIdx.x * 4;
  const float* xb = x + ((size_t)(b << 12)) * 512;
  float ax = 0.f, ay = 0.f, az = 0.f, aw = 0.f;
  #pragma unroll
  for (int wl = 0; wl < 4; wl++) {
    int y = wy * 2 + (wl >> 1), xc = wx * 2 + (wl & 1);
    const float4 v = *(const float4*)(xb + (size_t)(y * 64 + xc) * 512 + c0);
    ax += v.x; ay += v.y; az += v.z; aw += v.w;
    ushort4v o = { f2bf(v.x), f2bf(v.y), f2bf(v.z), f2bf(v.w) };
    *(ushort4v*)(xw + (size_t)(win * 4 + wl) * 512 + c0) = o;
  }
  ushort4v p = { f2bf(ax * 0.25f), f2bf(ay * 0.25f), f2bf(az * 0.25f), f2bf(aw * 0.25f) };
  *(ushort4v*)(pooled + (size_t)win * 512 + c0) = p;
}

// ---------- generic NT bf16 GEMM: C[M,N] = A[M,K] * Bt[N,K]^T ----------
template<int EPI>
__global__ __launch_bounds__(256)
void gemm_nt(const unsigned short* __restrict__ A0,
             const unsigned short* __restrict__ A1,
             const unsigned short* __restrict__ Bt,
             unsigned short* __restrict__ C0,
             unsigned short* __restrict__ C1,
             float* __restrict__ Cf,
             const float* __restrict__ bias,
             int M, int N, int K)
{
  __shared__ unsigned short Asm[128 * 64];
  __shared__ unsigned short Bsm[128 * 64];
  char* As = (char*)Asm; char* Bs = (char*)Bsm;
  const int tid = threadIdx.x;
  const int w = tid >> 6, l = tid & 63;
  const int ntiles = N >> 7;
  const int mt = blockIdx.x / ntiles, nt = blockIdx.x % ntiles;
  const int m0 = mt * 128, n0 = nt * 128;
  const unsigned short* A = (EPI == 2 && n0 >= 256) ? A1 : A0;

  const int wm = (w >> 1) * 64, wn = (w & 1) * 64;
  f32x4 acc[4][4];
  #pragma unroll
  for (int i = 0; i < 4; i++)
    #pragma unroll
    for (int j = 0; j < 4; j++) acc[i][j] = (f32x4){0.f, 0.f, 0.f, 0.f};

  for (int k0 = 0; k0 < K; k0 += 64) {
    bf16x8 av[4], bv[4];
    #pragma unroll
    for (int i = 0; i < 4; i++) {
      int r = i * 32 + w * 8 + (l >> 3);
      av[i] = *(const bf16x8*)(A  + (size_t)(m0 + r) * K + k0 + (l & 7) * 8);
      bv[i] = *(const bf16x8*)(Bt + (size_t)(n0 + r) * K + k0 + (l & 7) * 8);
    }
    __syncthreads();
    #pragma unroll
    for (int i = 0; i < 4; i++) {
      int r = i * 32 + w * 8 + (l >> 3);
      int off = (r * 128 + (l & 7) * 16) ^ ((r & 7) << 4);   // XOR-swizzle (G4)
      *(bf16x8*)(As + off) = av[i];
      *(bf16x8*)(Bs + off) = bv[i];
    }
    __syncthreads();
    #pragma unroll
    for (int kk = 0; kk < 2; kk++) {
      bf16x8 af[4], bfr[4];
      #pragma unroll
      for (int m = 0; m < 4; m++) {
        int r = wm + m * 16 + (l & 15);
        af[m] = *(const bf16x8*)(As + ((r * 128 + kk * 64 + (l >> 4) * 16) ^ ((r & 7) << 4)));
      }
      #pragma unroll
      for (int n = 0; n < 4; n++) {
        int r = wn + n * 16 + (l & 15);
        bfr[n] = *(const bf16x8*)(Bs + ((r * 128 + kk * 64 + (l >> 4) * 16) ^ ((r & 7) << 4)));
      }
      #pragma unroll
      for (int m = 0; m < 4; m++)
        #pragma unroll
        for (int n = 0; n < 4; n++)
          acc[m][n] = __builtin_amdgcn_mfma_f32_16x16x32_bf16(af[m], bfr[n], acc[m][n], 0, 0, 0);
    }
  }

  const int crow0 = m0 + wm, ccol0 = n0 + wn;
  #pragma unroll
  for (int m = 0; m < 4; m++) {
    #pragma unroll
    for (int n = 0; n < 4; n++) {
      #pragma unroll
      for (int j = 0; j < 4; j++) {
        int row = crow0 + m * 16 + (l >> 4) * 4 + j;
        int col = ccol0 + n * 16 + (l & 15);
        float v = acc[m][n][j];
        if (EPI == 0) {
          C0[(size_t)row * N + col] = f2bf(v);
        } else if (EPI == 1) {
          if (col < 256) C0[(size_t)row * 256 + col] = f2bf(v);
          else {
            int h = (col - 256) >> 6, d = (col - 256) & 63;
            int b = row >> 10, key = row & 1023;
            C1[(size_t)(((b * 4 + h) << 6) + d) * 1024 + key] = f2bf(v);
          }
        } else {
          float vv = v + bias[col];
          int b = row >> 12, r = row & 4095, t = r >> 2, wl = r & 3;
          int y = ((t >> 5) << 1) | (wl >> 1), xc = ((t & 31) << 1) | (wl & 1);
          Cf[(size_t)((b << 12) + y * 64 + xc) * 512 + col] = vv;
        }
      }
    }
  }
}

// ---------- K3: hifi 2x2-window attention. 1 wave = 1 window, all 4 heads ----------
__global__ __launch_bounds__(256)
void hifi_attn(const unsigned short* __restrict__ QKVQ, unsigned short* __restrict__ aoh)
{
  int widx = blockIdx.x * 4 + (threadIdx.x >> 6);
  int l = threadIdx.x & 63;
  int h = l >> 4, i = (l >> 2) & 3, j = l & 3;
  size_t r0 = (size_t)widx * 4;
  const unsigned short* qp = QKVQ + (r0 + i) * 1024 + h * 64;
  const unsigned short* kp = QKVQ + (r0 + j) * 1024 + 256 + h * 64;
  float s = 0.f;
  #pragma unroll
  for (int c = 0; c < 8; c++) {
    bf16x8 q8 = *(const bf16x8*)(qp + c * 8);
    bf16x8 k8 = *(const bf16x8*)(kp + c * 8);
    #pragma unroll
    for (int e = 0; e < 8; e++) s += (float)q8[e] * (float)k8[e];
  }
  // scale folded into Wq
  float mx = fmaxf(s, __shfl_xor(s, 1)); mx = fmaxf(mx, __shfl_xor(mx, 2));
  float p = __expf(s - mx);
  float sum = p + __shfl_xor(p, 1); sum += __shfl_xor(sum, 2);
  p /= sum;

  int dblk = l & 15;
  float o[4][4];
  #pragma unroll
  for (int ii = 0; ii < 4; ii++)
    #pragma unroll
    for (int e = 0; e < 4; e++) o[ii][e] = 0.f;
  #pragma unroll
  for (int jj = 0; jj < 4; jj++) {
    const unsigned short* vp = QKVQ + (r0 + jj) * 1024 + 512 + h * 64 + dblk * 4;
    ushort4v v4 = *(const ushort4v*)vp;
    #pragma unroll
    for (int ii = 0; ii < 4; ii++) {
      float pij = __shfl(p, (l & 48) + ii * 4 + jj);
      #pragma unroll
      for (int e = 0; e < 4; e++) o[ii][e] += pij * bf2f(v4[e]);
    }
  }
  #pragma unroll
  for (int ii = 0; ii < 4; ii++) {
    ushort4v ov = { f2bf(o[ii][0]), f2bf(o[ii][1]), f2bf(o[ii][2]), f2bf(o[ii][3]) };
    *(ushort4v*)(aoh + (r0 + ii) * 256 + h * 64 + dblk * 4) = ov;
  }
}

// ---------- K4: lofi flash attention, swapped-QK^T structure ----------
// block = (bh, qt128): 4 waves x 32 q-rows. KV chunk = 64 keys, 16 chunks,
// double-buffered LDS (1 barrier/chunk). S^T = mfma(K, Q) so softmax is
// per-lane over 16 keys + 2 shfl_xor. P -> LDS packed u32, PV reads b128.
__global__ __launch_bounds__(256)
void lofi_attn(const unsigned short* __restrict__ QKVQ,
               const unsigned short* __restrict__ kvk,
               const unsigned short* __restrict__ vT,
               unsigned short* __restrict__ aol)
{
  __shared__ unsigned short Kb[2][4096];   // [64 key][64 d]  (swizzled)
  __shared__ unsigned short Vb[2][4096];   // [64 d][64 key]  (swizzled)
  __shared__ unsigned short Pb[4][2048];   // per-wave P [32 qrow][64 key] (swizzled)

  const int tid = threadIdx.x, w = tid >> 6, l = tid & 63;
  const int bh = blockIdx.x >> 5, qt = blockIdx.x & 31;
  const int b = bh >> 2, h = bh & 3;
  const int g = l >> 4, lo = l & 15;
  const int qbase = (b << 12) + qt * 128 + w * 32;

  // Q B-fragments, resident all kernel (scale pre-folded into weights)
  bf16x8 qf[2][2];
  #pragma unroll
  for (int qg = 0; qg < 2; qg++)
    #pragma unroll
    for (int kk = 0; kk < 2; kk++)
      qf[qg][kk] = *(const bf16x8*)(QKVQ + (size_t)(qbase + qg * 16 + lo) * 1024
                                    + 768 + h * 64 + kk * 32 + g * 8);

  float m_run[2] = { -1e30f, -1e30f }, l_run[2] = { 0.f, 0.f };
  f32x4 accO[2][4];
  #pragma unroll
  for (int qg = 0; qg < 2; qg++)
    #pragma unroll
    for (int dt = 0; dt < 4; dt++) accO[qg][dt] = (f32x4){0.f, 0.f, 0.f, 0.f};

  // staging: 2 x 16B of K and V per thread per chunk
  const unsigned short* kptr = kvk + ((size_t)(b << 10) + (tid >> 3)) * 256 + h * 64 + (tid & 7) * 8;
  const unsigned short* vptr = vT + ((size_t)bh * 64 + (tid >> 3)) * 1024 + (tid & 7) * 8;
  const int srow = tid >> 3, sc = (tid & 7) * 16;
  const int soff = (srow * 128 + sc) ^ ((srow & 7) << 4);   // +4096 for row+32

  char* Pw = (char*)Pb[w];
  const int pswz = ((lo & 7) << 4);   // qrow swizzle bits (same for qg 0/1: row&7==lo&7)

  // prologue: chunk 0
  bf16x8 kr0 = *(const bf16x8*)(kptr);
  bf16x8 kr1 = *(const bf16x8*)(kptr + 32 * 256);
  bf16x8 vr0 = *(const bf16x8*)(vptr);
  bf16x8 vr1 = *(const bf16x8*)(vptr + 32 * 1024);
  *(bf16x8*)((char*)Kb[0] + soff) = kr0;
  *(bf16x8*)((char*)Kb[0] + soff + 4096) = kr1;
  *(bf16x8*)((char*)Vb[0] + soff) = vr0;
  *(bf16x8*)((char*)Vb[0] + soff + 4096) = vr1;
  __syncthreads();

  for (int t = 0; t < 16; t++) {
    const int cur = t & 1;
    char* Ks = (char*)Kb[cur];
    char* Vs = (char*)Vb[cur];

    if (t < 15) {   // issue next-chunk loads early (hide HBM/L2 latency under compute)
      kr0 = *(const bf16x8*)(kptr + (size_t)(t + 1) * 16384);
      kr1 = *(const bf16x8*)(kptr + (size_t)(t + 1) * 16384 + 32 * 256);
      vr0 = *(const bf16x8*)(vptr + (t + 1) * 64);
      vr1 = *(const bf16x8*)(vptr + (t + 1) * 64 + 32 * 1024);
    }

    // --- S^T[key 64][qrow 32] = K_chunk x Q^T ---
    f32x4 s[2][4];
    #pragma unroll
    for (int qg = 0; qg < 2; qg++)
      #pragma unroll
      for (int kt = 0; kt < 4; kt++) s[qg][kt] = (f32x4){0.f, 0.f, 0.f, 0.f};
    #pragma unroll
    for (int kt = 0; kt < 4; kt++) {
      const int krow = kt * 16 + lo;
      const int ksw = (krow & 7) << 4;
      bf16x8 kf0 = *(const bf16x8*)(Ks + ((krow * 128 + g * 16) ^ ksw));
      bf16x8 kf1 = *(const bf16x8*)(Ks + ((krow * 128 + 64 + g * 16) ^ ksw));
      s[0][kt] = __builtin_amdgcn_mfma_f32_16x16x32_bf16(kf0, qf[0][0], s[0][kt], 0, 0, 0);
      s[0][kt] = __builtin_amdgcn_mfma_f32_16x16x32_bf16(kf1, qf[0][1], s[0][kt], 0, 0, 0);
      s[1][kt] = __builtin_amdgcn_mfma_f32_16x16x32_bf16(kf0, qf[1][0], s[1][kt], 0, 0, 0);
      s[1][kt] = __builtin_amdgcn_mfma_f32_16x16x32_bf16(kf1, qf[1][1], s[1][kt], 0, 0, 0);
    }

    // --- online softmax, lane-local keys (qrow = lo per qg) ---
    #pragma unroll
    for (int qg = 0; qg < 2; qg++) {
      float pmax = -1e30f;
      #pragma unroll
      for (int kt = 0; kt < 4; kt++) {
        pmax = fmaxf(pmax, fmaxf(fmaxf(s[qg][kt][0], s[qg][kt][1]),
                                 fmaxf(s[qg][kt][2], s[qg][kt][3])));
      }
      pmax = fmaxf(pmax, __shfl_xor(pmax, 16));
      pmax = fmaxf(pmax, __shfl_xor(pmax, 32));
      if (__any(pmax > m_run[qg] + 8.f)) {          // defer-max (T13)
        float mnew = fmaxf(m_run[qg], pmax);
        float alpha = __expf(m_run[qg] - mnew);
        l_run[qg] *= alpha;
        m_run[qg] = mnew;
        #pragma unroll
        for (int j = 0; j < 4; j++) {
          float aj = __shfl(alpha, g * 4 + j);      // alpha for qrow'=(g*4+j)
          #pragma unroll
          for (int dt = 0; dt < 4; dt++) accO[qg][dt][j] *= aj;
        }
      }
      float rs = 0.f;
      const int prowb = (qg * 16 + lo) * 128;
      #pragma unroll
      for (int kt = 0; kt < 4; kt++) {
        float p0 = __expf(s[qg][kt][0] - m_run[qg]);
        float p1 = __expf(s[qg][kt][1] - m_run[qg]);
        float p2 = __expf(s[qg][kt][2] - m_run[qg]);
        float p3 = __expf(s[qg][kt][3] - m_run[qg]);
        rs += (p0 + p1) + (p2 + p3);
        unsigned int u0 = ((unsigned int)f2bf(p1) << 16) | f2bf(p0);
        unsigned int u1 = ((unsigned int)f2bf(p3) << 16) | f2bf(p2);
        int byte0 = prowb + kt * 32 + g * 8;        // key = kt*16 + g*4
        *(unsigned int*)(Pw + ((byte0) ^ pswz)) = u0;
        *(unsigned int*)(Pw + ((byte0 + 4) ^ pswz)) = u1;
      }
      rs += __shfl_xor(rs, 16);
      rs += __shfl_xor(rs, 32);
      l_run[qg] += rs;
    }

    // --- PV: O[32 qrow][64 d] += P[32][64] * V[64][64] ---
    #pragma unroll
    for (int ks = 0; ks < 2; ks++) {
      bf16x8 vf[4];
      #pragma unroll
      for (int dt = 0; dt < 4; dt++) {
        const int vrow = dt * 16 + lo;
        vf[dt] = *(const bf16x8*)(Vs + ((vrow * 128 + ks * 64 + g * 16) ^ ((vrow & 7) << 4)));
      }
      #pragma unroll
      for (int qg = 0; qg < 2; qg++) {
        const int prow = qg * 16 + lo;
        bf16x8 pa = *(const bf16x8*)(Pw + ((prow * 128 + ks * 64 + g * 16) ^ pswz));
        #pragma unroll
        for (int dt = 0; dt < 4; dt++)
          accO[qg][dt] = __builtin_amdgcn_mfma_f32_16x16x32_bf16(pa, vf[dt], accO[qg][dt], 0, 0, 0);
      }
    }

    if (t < 15) {
      *(bf16x8*)((char*)Kb[cur ^ 1] + soff) = kr0;
      *(bf16x8*)((char*)Kb[cur ^ 1] + soff + 4096) = kr1;
      *(bf16x8*)((char*)Vb[cur ^ 1] + soff) = vr0;
      *(bf16x8*)((char*)Vb[cur ^ 1] + soff + 4096) = vr1;
      __syncthreads();
    }
  }

  // epilogue: normalize + store
  #pragma unroll
  for (int qg = 0; qg < 2; qg++) {
    float invl = 1.f / l_run[qg];
    #pragma unroll
    for (int j = 0; j < 4; j++) {
      float ivj = __shfl(invl, g * 4 + j);
      const int row = qbase + qg * 16 + g * 4 + j;
      #pragma unroll
      for (int dt = 0; dt < 4; dt++)
        aol[(size_t)row * 256 + h * 64 + dt * 16 + lo] = f2bf(accO[qg][dt][j] * ivj);
    }
  }
}

// ---------- launch ----------
extern "C" void kernel_launch(void* const* d_in, const int* in_sizes, int n_in,
                              void* d_out, int out_size, void* d_ws, size_t ws_size,
                              hipStream_t stream) {
  (void)in_sizes; (void)n_in; (void)out_size; (void)ws_size;
  const float* x     = (const float*)d_in[0];
  const float* lqw   = (const float*)d_in[3];
  const float* lkvw  = (const float*)d_in[4];
  const float* lpw   = (const float*)d_in[5];
  const float* lpb   = (const float*)d_in[6];
  const float* hqkvw = (const float*)d_in[7];
  const float* hpw   = (const float*)d_in[8];
  const float* hpb   = (const float*)d_in[9];

  char* ws = (char*)d_ws;
  unsigned short* W1T    = (unsigned short*)(ws + 0);
  unsigned short* W2T    = (unsigned short*)(ws + 1048576);
  unsigned short* W3T    = (unsigned short*)(ws + 1572864);
  float*          bcat   = (float*)        (ws + 1835008);
  unsigned short* xw     = (unsigned short*)(ws + 2097152);
  unsigned short* pooled = (unsigned short*)(ws + 35651584);
  unsigned short* kvk    = (unsigned short*)(ws + 44040192);
  unsigned short* vT     = (unsigned short*)(ws + 48234496);
  unsigned short* aoh    = (unsigned short*)(ws + 52428800);
  unsigned short* aol    = (unsigned short*)(ws + 69206016);
  unsigned short* QKVQ   = (unsigned short*)d_out;   // 64 MiB scratch, overwritten by proj
  float*          out    = (float*)d_out;

  prep_weights<<<3586, 256, 0, stream>>>(lqw, lkvw, lpw, lpb, hqkvw, hpw, hpb,
                                         W1T, W2T, W3T, bcat);
  prep_x<<<8192, 128, 0, stream>>>(x, xw, pooled);
  gemm_nt<0><<<2048, 256, 0, stream>>>(xw, nullptr, W1T, QKVQ, nullptr, nullptr, nullptr,
                                       32768, 1024, 512);
  gemm_nt<1><<<256, 256, 0, stream>>>(pooled, nullptr, W2T, kvk, vT, nullptr, nullptr,
                                      8192, 512, 512);
  hifi_attn<<<2048, 256, 0, stream>>>(QKVQ, aoh);
  lofi_attn<<<1024, 256, 0, stream>>>(QKVQ, kvk, vT, aol);
  gemm_nt<2><<<1024, 256, 0, stream>>>(aoh, aol, W3T, nullptr, nullptr, out, bcat,
                                       32768, 512, 256);
}

// Round 3
// 194.910 us; speedup vs baseline: 1.4678x; 1.0573x over previous
//
#include <hip/hip_runtime.h>
#include <hip/hip_bf16.h>

// ---------- types ----------
typedef __bf16 bf16x8 __attribute__((ext_vector_type(8)));      // 16B, MFMA A/B frag
typedef float  f32x4  __attribute__((ext_vector_type(4)));      // MFMA C/D frag
typedef unsigned short ushort4v __attribute__((ext_vector_type(4)));

static __device__ __forceinline__ float bf2f(unsigned short u) {
  union { float f; unsigned int i; } v; v.i = ((unsigned int)u) << 16; return v.f;
}
static __device__ __forceinline__ unsigned short f2bf(float f) {
  unsigned int x = __float_as_uint(f);
  x += 0x7fffu + ((x >> 16) & 1u);   // RNE (inputs are NaN-free)
  return (unsigned short)(x >> 16);
}

// async global->LDS, 16B per lane; dest = wave-uniform base + lane*16
static __device__ __forceinline__ void gload_lds16(const unsigned short* g, unsigned short* l) {
  __builtin_amdgcn_global_load_lds(
      (const __attribute__((address_space(1))) unsigned int*)g,
      (__attribute__((address_space(3))) unsigned int*)l, 16, 0, 0);
}

// 0.125 (softmax scale) * log2(e): attention kernels use exp2 directly.
#define QSCL 0.18033688011112042f

// ---------- K0: weights -> bf16, transposed to [N][K] ----------
// W1T [1024][512]: cols 0..255 hifi Wq (x QSCL), 256..511 Wk, 512..767 Wv,
//                  768..1023 lofi Wq (x QSCL)
__global__ __launch_bounds__(256)
void prep_weights(const float* __restrict__ lq,  const float* __restrict__ lkv,
                  const float* __restrict__ lpw, const float* __restrict__ lpb,
                  const float* __restrict__ hqkv,const float* __restrict__ hpw,
                  const float* __restrict__ hpb,
                  unsigned short* __restrict__ W1T, unsigned short* __restrict__ W2T,
                  unsigned short* __restrict__ W3T, float* __restrict__ bcat)
{
  int idx = blockIdx.x * 256 + threadIdx.x;
  const int T1 = 524288, T2 = T1 + 262144, T3 = T2 + 131072, T4 = T3 + 512;
  if (idx >= T4) return;
  if (idx < T1) {
    int n = idx >> 9, k = idx & 511;
    float v = (n < 768) ? hqkv[k * 768 + n] : lq[k * 256 + (n - 768)];
    if (n < 256 || n >= 768) v *= QSCL;     // fold scale*log2e into Wq
    W1T[idx] = f2bf(v);
  } else if (idx < T2) {
    int i2 = idx - T1; int n = i2 >> 9, k = i2 & 511;
    W2T[i2] = f2bf(lkv[k * 512 + n]);
  } else if (idx < T3) {
    int i3 = idx - T2; int n = i3 >> 8, k = i3 & 255;
    float v = (n < 256) ? hpw[k * 256 + n] : lpw[k * 256 + (n - 256)];
    W3T[i3] = f2bf(v);
  } else {
    int i4 = idx - T3;
    bcat[i4] = (i4 < 256) ? hpb[i4] : lpb[i4 - 256];
  }
}

// ---------- K0b: x -> xw bf16 (window-major) + pooled bf16 (window mean) ----------
__global__ __launch_bounds__(128)
void prep_x(const float* __restrict__ x, unsigned short* __restrict__ xw,
            unsigned short* __restrict__ pooled)
{
  int win = blockIdx.x;                 // b*1024 + t
  int b = win >> 10, t = win & 1023;
  int wy = t >> 5, wx = t & 31;
  int c0 = threadIdx.x * 4;
  const float* xb = x + ((size_t)(b << 12)) * 512;
  float ax = 0.f, ay = 0.f, az = 0.f, aw = 0.f;
  #pragma unroll
  for (int wl = 0; wl < 4; wl++) {
    int y = wy * 2 + (wl >> 1), xc = wx * 2 + (wl & 1);
    const float4 v = *(const float4*)(xb + (size_t)(y * 64 + xc) * 512 + c0);
    ax += v.x; ay += v.y; az += v.z; aw += v.w;
    ushort4v o = { f2bf(v.x), f2bf(v.y), f2bf(v.z), f2bf(v.w) };
    *(ushort4v*)(xw + (size_t)(win * 4 + wl) * 512 + c0) = o;
  }
  ushort4v p = { f2bf(ax * 0.25f), f2bf(ay * 0.25f), f2bf(az * 0.25f), f2bf(aw * 0.25f) };
  *(ushort4v*)(pooled + (size_t)win * 512 + c0) = p;
}

// ---------- generic NT bf16 GEMM: C[M,N] = A[M,K] * Bt[N,K]^T ----------
// Staging: global_load_lds width-16, linear LDS dest + source-chunk XOR
// pre-swizzle; reads use the matching XOR swizzle (conflict-free).
template<int EPI>
__global__ __launch_bounds__(256)
void gemm_nt(const unsigned short* __restrict__ A0,
             const unsigned short* __restrict__ A1,
             const unsigned short* __restrict__ Bt,
             unsigned short* __restrict__ C0,
             unsigned short* __restrict__ C1,
             float* __restrict__ Cf,
             const float* __restrict__ bias,
             int M, int N, int K)
{
  __shared__ unsigned short Asm[128 * 64];
  __shared__ unsigned short Bsm[128 * 64];
  char* As = (char*)Asm; char* Bs = (char*)Bsm;
  const int tid = threadIdx.x;
  const int w = tid >> 6, l = tid & 63;
  const int ntiles = N >> 7;
  const int mt = blockIdx.x / ntiles, nt = blockIdx.x % ntiles;
  const int m0 = mt * 128, n0 = nt * 128;
  const unsigned short* A = (EPI == 2 && n0 >= 256) ? A1 : A0;

  const int wm = (w >> 1) * 64, wn = (w & 1) * 64;
  f32x4 acc[4][4];
  #pragma unroll
  for (int i = 0; i < 4; i++)
    #pragma unroll
    for (int j = 0; j < 4; j++) acc[i][j] = (f32x4){0.f, 0.f, 0.f, 0.f};

  const int srr = w * 8 + (l >> 3);         // staging row (+i*32)
  const int sc = ((l & 7) ^ (l >> 3)) * 8;  // pre-swizzled source col (elements)

  for (int k0 = 0; k0 < K; k0 += 64) {
    #pragma unroll
    for (int i = 0; i < 4; i++) {
      gload_lds16(A  + (size_t)(m0 + i * 32 + srr) * K + k0 + sc, &Asm[(i * 32 + w * 8) * 64]);
      gload_lds16(Bt + (size_t)(n0 + i * 32 + srr) * K + k0 + sc, &Bsm[(i * 32 + w * 8) * 64]);
    }
    __syncthreads();
    #pragma unroll
    for (int kk = 0; kk < 2; kk++) {
      bf16x8 af[4], bfr[4];
      #pragma unroll
      for (int m = 0; m < 4; m++) {
        int r = wm + m * 16 + (l & 15);
        af[m] = *(const bf16x8*)(As + ((r * 128 + kk * 64 + (l >> 4) * 16) ^ ((r & 7) << 4)));
      }
      #pragma unroll
      for (int n = 0; n < 4; n++) {
        int r = wn + n * 16 + (l & 15);
        bfr[n] = *(const bf16x8*)(Bs + ((r * 128 + kk * 64 + (l >> 4) * 16) ^ ((r & 7) << 4)));
      }
      #pragma unroll
      for (int m = 0; m < 4; m++)
        #pragma unroll
        for (int n = 0; n < 4; n++)
          acc[m][n] = __builtin_amdgcn_mfma_f32_16x16x32_bf16(af[m], bfr[n], acc[m][n], 0, 0, 0);
    }
    __syncthreads();
  }

  const int crow0 = m0 + wm, ccol0 = n0 + wn;
  #pragma unroll
  for (int m = 0; m < 4; m++) {
    #pragma unroll
    for (int n = 0; n < 4; n++) {
      #pragma unroll
      for (int j = 0; j < 4; j++) {
        int row = crow0 + m * 16 + (l >> 4) * 4 + j;
        int col = ccol0 + n * 16 + (l & 15);
        float v = acc[m][n][j];
        if (EPI == 0) {
          C0[(size_t)row * N + col] = f2bf(v);
        } else if (EPI == 1) {
          if (col < 256) C0[(size_t)row * 256 + col] = f2bf(v);
          else {
            int h = (col - 256) >> 6, d = (col - 256) & 63;
            int b = row >> 10, key = row & 1023;
            C1[(size_t)(((b * 4 + h) << 6) + d) * 1024 + key] = f2bf(v);
          }
        } else {
          float vv = v + bias[col];
          int b = row >> 12, r = row & 4095, t = r >> 2, wl = r & 3;
          int y = ((t >> 5) << 1) | (wl >> 1), xc = ((t & 31) << 1) | (wl & 1);
          Cf[(size_t)((b << 12) + y * 64 + xc) * 512 + col] = vv;
        }
      }
    }
  }
}

// ---------- K3: hifi 2x2-window attention. 1 wave = 1 window, all 4 heads ----------
__global__ __launch_bounds__(256)
void hifi_attn(const unsigned short* __restrict__ QKVQ, unsigned short* __restrict__ aoh)
{
  int widx = blockIdx.x * 4 + (threadIdx.x >> 6);
  int l = threadIdx.x & 63;
  int h = l >> 4, i = (l >> 2) & 3, j = l & 3;
  size_t r0 = (size_t)widx * 4;
  const unsigned short* qp = QKVQ + (r0 + i) * 1024 + h * 64;
  const unsigned short* kp = QKVQ + (r0 + j) * 1024 + 256 + h * 64;
  float s = 0.f;
  #pragma unroll
  for (int c = 0; c < 8; c++) {
    bf16x8 q8 = *(const bf16x8*)(qp + c * 8);
    bf16x8 k8 = *(const bf16x8*)(kp + c * 8);
    #pragma unroll
    for (int e = 0; e < 8; e++) s += (float)q8[e] * (float)k8[e];
  }
  // scale*log2e folded into Wq -> exp2 softmax
  float mx = fmaxf(s, __shfl_xor(s, 1)); mx = fmaxf(mx, __shfl_xor(mx, 2));
  float p = __builtin_amdgcn_exp2f(s - mx);
  float sum = p + __shfl_xor(p, 1); sum += __shfl_xor(sum, 2);
  p /= sum;

  int dblk = l & 15;
  float o[4][4];
  #pragma unroll
  for (int ii = 0; ii < 4; ii++)
    #pragma unroll
    for (int e = 0; e < 4; e++) o[ii][e] = 0.f;
  #pragma unroll
  for (int jj = 0; jj < 4; jj++) {
    const unsigned short* vp = QKVQ + (r0 + jj) * 1024 + 512 + h * 64 + dblk * 4;
    ushort4v v4 = *(const ushort4v*)vp;
    #pragma unroll
    for (int ii = 0; ii < 4; ii++) {
      float pij = __shfl(p, (l & 48) + ii * 4 + jj);
      #pragma unroll
      for (int e = 0; e < 4; e++) o[ii][e] += pij * bf2f(v4[e]);
    }
  }
  #pragma unroll
  for (int ii = 0; ii < 4; ii++) {
    ushort4v ov = { f2bf(o[ii][0]), f2bf(o[ii][1]), f2bf(o[ii][2]), f2bf(o[ii][3]) };
    *(ushort4v*)(aoh + (r0 + ii) * 256 + h * 64 + dblk * 4) = ov;
  }
}

// ---------- K4: lofi flash attention, swapped-QK^T, P-in-registers ----------
// Kb rows are staged with a bit-permuted key order c_k(r)={r5,r3,r2,r4,r1,r0}
// so each lane's softmax outputs ARE its PV A-fragment (no P LDS/shuffles).
// Vb stays in natural key order. Softmax is permutation-invariant.
__global__ __launch_bounds__(256)
void lofi_attn(const unsigned short* __restrict__ QKVQ,
               const unsigned short* __restrict__ kvk,
               const unsigned short* __restrict__ vT,
               unsigned short* __restrict__ aol)
{
  __shared__ unsigned short Kb[2][4096];   // [64 keypos][64 d]  swizzled
  __shared__ unsigned short Vb[2][4096];   // [64 d][64 key]     swizzled

  const int tid = threadIdx.x, w = tid >> 6, l = tid & 63;
  const int bid = (int)blockIdx.x;
  const int swz = (bid & 7) * 128 + (bid >> 3);   // XCD-cluster same-bh blocks
  const int bh = swz >> 5, qt = swz & 31;
  const int b = bh >> 2, h = bh & 3;
  const int g = l >> 4, lo = l & 15;
  const int qbase = (b << 12) + qt * 128 + w * 32;

  // Q B-fragments, resident all kernel (scale*log2e pre-folded)
  bf16x8 qf[2][2];
  #pragma unroll
  for (int qg = 0; qg < 2; qg++)
    #pragma unroll
    for (int kk = 0; kk < 2; kk++)
      qf[qg][kk] = *(const bf16x8*)(QKVQ + (size_t)(qbase + qg * 16 + lo) * 1024
                                    + 768 + h * 64 + kk * 32 + g * 8);

  float m_run[2] = { -1e30f, -1e30f }, l_run[2] = { 0.f, 0.f };
  f32x4 accO[2][4];
  #pragma unroll
  for (int qg = 0; qg < 2; qg++)
    #pragma unroll
    for (int dt = 0; dt < 4; dt++) accO[qg][dt] = (f32x4){0.f, 0.f, 0.f, 0.f};

  // gload_lds staging geometry (linear dest, pre-swizzled source)
  const int rr = w * 8 + (l >> 3);                                 // region row 0..31
  const int ck = (rr & 0x23) | ((rr & 0x0C) << 1) | ((rr & 0x10) >> 2);  // key perm
  const int cs = ((l & 7) ^ (l >> 3)) * 8;                         // chunk pre-swizzle
  const unsigned short* kg0 = kvk + ((size_t)(b << 10) + ck) * 256 + h * 64 + cs;
  const unsigned short* vg0 = vT + ((size_t)bh * 64 + rr) * 1024 + cs;

#define STAGE(buf, tt) do {                                        \
    const unsigned short* kgp = kg0 + (size_t)(tt) * 16384;        \
    const unsigned short* vgp = vg0 + (tt) * 64;                   \
    gload_lds16(kgp,         &Kb[buf][w * 512]);                   \
    gload_lds16(kgp + 8192,  &Kb[buf][2048 + w * 512]);            \
    gload_lds16(vgp,         &Vb[buf][w * 512]);                   \
    gload_lds16(vgp + 32768, &Vb[buf][2048 + w * 512]);            \
  } while (0)

  STAGE(0, 0);
  __syncthreads();

  for (int t = 0; t < 16; t++) {
    const int cur = t & 1;
    if (t < 15) STAGE(cur ^ 1, t + 1);     // async, drains at end-of-iter barrier
    const char* Ks = (const char*)Kb[cur];
    const char* Vs = (const char*)Vb[cur];

    // --- S^T[keypos 64][qrow 32] = K x Q^T ---
    f32x4 s[2][4];
    #pragma unroll
    for (int qg = 0; qg < 2; qg++)
      #pragma unroll
      for (int kt = 0; kt < 4; kt++) s[qg][kt] = (f32x4){0.f, 0.f, 0.f, 0.f};
    #pragma unroll
    for (int kt = 0; kt < 4; kt++) {
      const int krow = kt * 16 + lo;
      const int ksw = (krow & 7) << 4;
      bf16x8 kf0 = *(const bf16x8*)(Ks + ((krow * 128 + g * 16) ^ ksw));
      bf16x8 kf1 = *(const bf16x8*)(Ks + ((krow * 128 + 64 + g * 16) ^ ksw));
      s[0][kt] = __builtin_amdgcn_mfma_f32_16x16x32_bf16(kf0, qf[0][0], s[0][kt], 0, 0, 0);
      s[0][kt] = __builtin_amdgcn_mfma_f32_16x16x32_bf16(kf1, qf[0][1], s[0][kt], 0, 0, 0);
      s[1][kt] = __builtin_amdgcn_mfma_f32_16x16x32_bf16(kf0, qf[1][0], s[1][kt], 0, 0, 0);
      s[1][kt] = __builtin_amdgcn_mfma_f32_16x16x32_bf16(kf1, qf[1][1], s[1][kt], 0, 0, 0);
    }

    // --- online softmax (log2 units) + pack A-fragments in registers ---
    bf16x8 pp[2][2];
    #pragma unroll
    for (int qg = 0; qg < 2; qg++) {
      float pmax = -1e30f;
      #pragma unroll
      for (int kt = 0; kt < 4; kt++)
        pmax = fmaxf(pmax, fmaxf(fmaxf(s[qg][kt][0], s[qg][kt][1]),
                                 fmaxf(s[qg][kt][2], s[qg][kt][3])));
      pmax = fmaxf(pmax, __shfl_xor(pmax, 16));
      pmax = fmaxf(pmax, __shfl_xor(pmax, 32));
      if (__any(pmax > m_run[qg] + 8.f)) {          // defer-max (T13)
        float mnew = fmaxf(m_run[qg], pmax);
        float alpha = __builtin_amdgcn_exp2f(m_run[qg] - mnew);
        l_run[qg] *= alpha;
        m_run[qg] = mnew;
        #pragma unroll
        for (int j = 0; j < 4; j++) {
          float aj = __shfl(alpha, g * 4 + j);      // alpha of qrow g*4+j
          #pragma unroll
          for (int dt = 0; dt < 4; dt++) accO[qg][dt][j] *= aj;
        }
      }
      float rs = 0.f;
      #pragma unroll
      for (int kt = 0; kt < 4; kt++) {
        float e0 = __builtin_amdgcn_exp2f(s[qg][kt][0] - m_run[qg]);
        float e1 = __builtin_amdgcn_exp2f(s[qg][kt][1] - m_run[qg]);
        float e2 = __builtin_amdgcn_exp2f(s[qg][kt][2] - m_run[qg]);
        float e3 = __builtin_amdgcn_exp2f(s[qg][kt][3] - m_run[qg]);
        rs += (e0 + e1) + (e2 + e3);
        pp[qg][kt >> 1][(kt & 1) * 4 + 0] = (__bf16)e0;
        pp[qg][kt >> 1][(kt & 1) * 4 + 1] = (__bf16)e1;
        pp[qg][kt >> 1][(kt & 1) * 4 + 2] = (__bf16)e2;
        pp[qg][kt >> 1][(kt & 1) * 4 + 3] = (__bf16)e3;
      }
      rs += __shfl_xor(rs, 16);
      rs += __shfl_xor(rs, 32);
      l_run[qg] += rs;
    }

    // --- PV: O[32 qrow][64 d] += P * V (P already in A-frag layout) ---
    #pragma unroll
    for (int ks = 0; ks < 2; ks++) {
      bf16x8 vf[4];
      #pragma unroll
      for (int dt = 0; dt < 4; dt++) {
        const int vrow = dt * 16 + lo;
        vf[dt] = *(const bf16x8*)(Vs + ((vrow * 128 + ks * 64 + g * 16) ^ ((vrow & 7) << 4)));
      }
      #pragma unroll
      for (int qg = 0; qg < 2; qg++)
        #pragma unroll
        for (int dt = 0; dt < 4; dt++)
          accO[qg][dt] = __builtin_amdgcn_mfma_f32_16x16x32_bf16(pp[qg][ks], vf[dt], accO[qg][dt], 0, 0, 0);
    }
    __syncthreads();
  }
#undef STAGE

  // epilogue: normalize + store
  #pragma unroll
  for (int qg = 0; qg < 2; qg++) {
    float invl = 1.f / l_run[qg];
    #pragma unroll
    for (int j = 0; j < 4; j++) {
      float ivj = __shfl(invl, g * 4 + j);
      const int row = qbase + qg * 16 + g * 4 + j;
      #pragma unroll
      for (int dt = 0; dt < 4; dt++)
        aol[(size_t)row * 256 + h * 64 + dt * 16 + lo] = f2bf(accO[qg][dt][j] * ivj);
    }
  }
}

// ---------- launch ----------
extern "C" void kernel_launch(void* const* d_in, const int* in_sizes, int n_in,
                              void* d_out, int out_size, void* d_ws, size_t ws_size,
                              hipStream_t stream) {
  (void)in_sizes; (void)n_in; (void)out_size; (void)ws_size;
  const float* x     = (const float*)d_in[0];
  const float* lqw   = (const float*)d_in[3];
  const float* lkvw  = (const float*)d_in[4];
  const float* lpw   = (const float*)d_in[5];
  const float* lpb   = (const float*)d_in[6];
  const float* hqkvw = (const float*)d_in[7];
  const float* hpw   = (const float*)d_in[8];
  const float* hpb   = (const float*)d_in[9];

  char* ws = (char*)d_ws;
  unsigned short* W1T    = (unsigned short*)(ws + 0);
  unsigned short* W2T    = (unsigned short*)(ws + 1048576);
  unsigned short* W3T    = (unsigned short*)(ws + 1572864);
  float*          bcat   = (float*)        (ws + 1835008);
  unsigned short* xw     = (unsigned short*)(ws + 2097152);
  unsigned short* pooled = (unsigned short*)(ws + 35651584);
  unsigned short* kvk    = (unsigned short*)(ws + 44040192);
  unsigned short* vT     = (unsigned short*)(ws + 48234496);
  unsigned short* aoh    = (unsigned short*)(ws + 52428800);
  unsigned short* aol    = (unsigned short*)(ws + 69206016);
  unsigned short* QKVQ   = (unsigned short*)d_out;   // 64 MiB scratch, overwritten by proj
  float*          out    = (float*)d_out;

  prep_weights<<<3586, 256, 0, stream>>>(lqw, lkvw, lpw, lpb, hqkvw, hpw, hpb,
                                         W1T, W2T, W3T, bcat);
  prep_x<<<8192, 128, 0, stream>>>(x, xw, pooled);
  gemm_nt<0><<<2048, 256, 0, stream>>>(xw, nullptr, W1T, QKVQ, nullptr, nullptr, nullptr,
                                       32768, 1024, 512);
  gemm_nt<1><<<256, 256, 0, stream>>>(pooled, nullptr, W2T, kvk, vT, nullptr, nullptr,
                                      8192, 512, 512);
  hifi_attn<<<2048, 256, 0, stream>>>(QKVQ, aoh);
  lofi_attn<<<1024, 256, 0, stream>>>(QKVQ, kvk, vT, aol);
  gemm_nt<2><<<1024, 256, 0, stream>>>(aoh, aol, W3T, nullptr, nullptr, out, bcat,
                                       32768, 512, 256);
}